// Round 4
// baseline (17.280 us; speedup 1.0000x reference)
//
#include <hip/hip_runtime.h>
#include <hip/hip_bf16.h>

// Problem constants (fixed by setup_inputs)
#define BB  64      // batches
#define NMM 32      // motifs per batch
#define HH  256     // hidden
#define LFD 16      // ligand feature dim
#define NLA 128     // ligand atoms per batch (NMM*4)

// Softmax over motifs (axis=1) is shift-invariant: protein_rep/residue_rep/
// ligand_rep/b_mlp/b_lig terms are constant per batch row and cancel exactly.
// logit[b,m] (up to a per-batch constant) =
//     emb_table[wid[b,m]] . w4  +  motif_feat_sum[b,m] . (W_lig @ w5)
//
// One wave per batch: zero LDS, zero barriers, all comms via shuffles.

__device__ __forceinline__ float dot4(float4 a, float4 b) {
  return a.x * b.x + a.y * b.y + a.z * b.z + a.w * b.w;
}

__global__ __launch_bounds__(256) void score_kernel(
    const float* __restrict__ lig_feat,    // [B*128][16]
    const int*   __restrict__ wids,        // [B*32]
    const float* __restrict__ W_lig,       // [16][256]
    const float* __restrict__ emb_table,   // [501][256]
    const float* __restrict__ W_mlp,       // [1280][1]
    float* __restrict__ out)               // [64*32] vals, then [64*32] idx
{
  const int t    = threadIdx.x;
  const int lane = t & 63;
  const int wave = t >> 6;
  const int b    = blockIdx.x * 4 + wave;  // this wave's batch
  const int m    = lane >> 1;              // motif (2 lanes per motif)
  const int half = lane & 1;               // which 128-channel half

  // ---- head of the dependent chain: wid for this motif ----
  const int wid = wids[b * NMM + m];

  // ---- independent loads: 2 ligand atom rows per lane ----
  const int a0 = b * NLA + m * 4 + half * 2;    // atoms a0, a0+1 (contiguous)
  const float4* pa = (const float4*)(lig_feat + (size_t)a0 * LFD);
  const float4 r00 = pa[0], r01 = pa[1], r02 = pa[2], r03 = pa[3];
  const float4 r10 = pa[4], r11 = pa[5], r12 = pa[6], r13 = pa[7];

  // ---- wl5[f] = sum_h W_lig[f,h]*w5[h]; f = lane>>2, 4 lanes x 64 h each ----
  float wl;
  {
    const int f = lane >> 2, sub = lane & 3;
    const float4* wlr = (const float4*)(W_lig + f * HH + sub * 64);
    const float4* w5r = (const float4*)(W_mlp + 4 * HH + sub * 64);
    float s0 = 0.f, s1 = 0.f, s2 = 0.f, s3 = 0.f;
#pragma unroll
    for (int j = 0; j < 16; j += 4) {
      s0 += dot4(wlr[j],   w5r[j]);
      s1 += dot4(wlr[j+1], w5r[j+1]);
      s2 += dot4(wlr[j+2], w5r[j+2]);
      s3 += dot4(wlr[j+3], w5r[j+3]);
    }
    float s = (s0 + s1) + (s2 + s3);
    s += __shfl_xor(s, 1);
    s += __shfl_xor(s, 2);
    wl = s;                      // wl5[f] in every lane of the 4-group
  }

  // ---- e4 = emb_row . w4 over this lane's 128 channels ----
  float e4;
  {
    const float4* er  = (const float4*)(emb_table + (size_t)wid * HH + half * 128);
    const float4* w4p = (const float4*)(W_mlp + 3 * HH + half * 128);
    float acc[4] = {0.f, 0.f, 0.f, 0.f};
#pragma unroll 8
    for (int k = 0; k < 32; ++k) acc[k & 3] += dot4(er[k], w4p[k]);
    e4 = (acc[0] + acc[1]) + (acc[2] + acc[3]);
    e4 += __shfl_xor(e4, 1);     // full row dot in both lanes of the pair
  }

  // ---- broadcast wl5[0..15] to all lanes ----
  float4 wv0, wv1, wv2, wv3;
  {
    float w[16];
#pragma unroll
    for (int ff = 0; ff < 16; ++ff) w[ff] = __shfl(wl, ff * 4);
    wv0 = make_float4(w[0],  w[1],  w[2],  w[3]);
    wv1 = make_float4(w[4],  w[5],  w[6],  w[7]);
    wv2 = make_float4(w[8],  w[9],  w[10], w[11]);
    wv3 = make_float4(w[12], w[13], w[14], w[15]);
  }

  // ---- t5 = motif_feat_sum . wl5 (2 atoms here + 2 in the paired lane) ----
  float t5 = dot4(r00, wv0) + dot4(r01, wv1) + dot4(r02, wv2) + dot4(r03, wv3)
           + dot4(r10, wv0) + dot4(r11, wv1) + dot4(r12, wv2) + dot4(r13, wv3);
  t5 += __shfl_xor(t5, 1);       // 4-atom motif sum

  // ---- softmax over 32 motifs (values pair-duplicated across 64 lanes) ----
  const float x = e4 + t5;
  float mx = x;
  mx = fmaxf(mx, __shfl_xor(mx, 1));
  mx = fmaxf(mx, __shfl_xor(mx, 2));
  mx = fmaxf(mx, __shfl_xor(mx, 4));
  mx = fmaxf(mx, __shfl_xor(mx, 8));
  mx = fmaxf(mx, __shfl_xor(mx, 16));
  mx = fmaxf(mx, __shfl_xor(mx, 32));
  const float ex = expf(x - mx);
  float sm = ex;
  sm += __shfl_xor(sm, 1);       // adds exact duplicate -> 2*ex
  sm += __shfl_xor(sm, 2);
  sm += __shfl_xor(sm, 4);
  sm += __shfl_xor(sm, 8);
  sm += __shfl_xor(sm, 16);
  sm += __shfl_xor(sm, 32);      // = 2 * sum over 32 motifs
  const float sc = ex / (0.5f * sm);

  // ---- full stable descending rank (ties -> lower motif index first) ----
  int rank = 0;
#pragma unroll
  for (int j = 0; j < NMM; ++j) {
    const float sj = __shfl(sc, 2 * j);
    rank += (sj > sc) || (sj == sc && j < m);
  }
  if (half == 0) {
    out[b * NMM + rank] = sc;                    // vals
    out[BB * NMM + b * NMM + rank] = (float)m;   // idx (as float)
  }
}

extern "C" void kernel_launch(void* const* d_in, const int* in_sizes, int n_in,
                              void* d_out, int out_size, void* d_ws, size_t ws_size,
                              hipStream_t stream) {
  const float* lig_feat    = (const float*)d_in[2];
  const int*   ligand_wids = (const int*)d_in[7];
  const float* W_lig       = (const float*)d_in[14];
  const float* emb_table   = (const float*)d_in[16];
  const float* W_mlp       = (const float*)d_in[18];
  float* out = (float*)d_out;

  score_kernel<<<BB / 4, 256, 0, stream>>>(lig_feat, ligand_wids, W_lig,
                                           emb_table, W_mlp, out);
}

// Round 5
// 10.785 us; speedup vs baseline: 1.6023x; 1.6023x over previous
//
#include <hip/hip_runtime.h>
#include <hip/hip_bf16.h>

// Problem constants (fixed by setup_inputs)
#define BB  64      // batches
#define NMM 32      // motifs per batch
#define HH  256     // hidden
#define LFD 16      // ligand feature dim
#define NLA 128     // ligand atoms per batch (NMM*4)

// Softmax over motifs (axis=1) is shift-invariant: protein_rep/residue_rep/
// ligand_rep/b_mlp/b_lig terms are constant per batch row and cancel exactly.
// logit[b,m] (up to a per-batch constant) =
//     emb_table[wid[b,m]] . w4  +  motif_feat_sum[b,m] . (W_lig @ w5)
//
// 512 threads/block, disjoint wave roles, ONE barrier. Max 16 float4 loads
// per lane -> short serial VMEM chains, 512 waves device-wide for latency
// hiding (R4 lesson: never concentrate loads into few waves).

__device__ __forceinline__ float dot4(float4 a, float4 b) {
  return a.x * b.x + a.y * b.y + a.z * b.z + a.w * b.w;
}

__global__ __launch_bounds__(512) void score_kernel(
    const float* __restrict__ lig_feat,    // [B*128][16]
    const int*   __restrict__ wids,        // [B*32]
    const float* __restrict__ W_lig,       // [16][256]
    const float* __restrict__ emb_table,   // [501][256]
    const float* __restrict__ W_mlp,       // [1280][1]
    float* __restrict__ out)               // [64*32] vals, then [64*32] idx
{
  const int b = blockIdx.x;
  const int t = threadIdx.x;

  __shared__ float slog[NMM];          // e4 per motif
  __shared__ float smfs[NMM][LFD];     // motif feature sums
  __shared__ float swl5[LFD];          // W_lig @ w5

  if (t < 256) {
    // ---- e4[m] = emb_table[wid] . w4 : 8 lanes per motif, 32 ch each ----
    const int m = t >> 3;
    const int c = t & 7;
    const int wid = wids[b * NMM + m];
    const float4* er  = (const float4*)(emb_table + (size_t)wid * HH) + c * 8;
    const float4* w4p = (const float4*)(W_mlp + 3 * HH) + c * 8;
    float s = dot4(er[0], w4p[0]) + dot4(er[1], w4p[1])
            + dot4(er[2], w4p[2]) + dot4(er[3], w4p[3])
            + dot4(er[4], w4p[4]) + dot4(er[5], w4p[5])
            + dot4(er[6], w4p[6]) + dot4(er[7], w4p[7]);
    s += __shfl_xor(s, 1); s += __shfl_xor(s, 2); s += __shfl_xor(s, 4);
    if (c == 0) slog[m] = s;
  } else if (t < 384) {
    // ---- motif feature sums: 1 atom per lane, 4-lane groups ----
    const int ta = t - 256;                       // atom 0..127 of this batch
    const float4* p = (const float4*)(lig_feat + (size_t)(b * NLA + ta) * LFD);
    const float4 q0 = p[0], q1 = p[1], q2 = p[2], q3 = p[3];
    float a[LFD] = {q0.x,q0.y,q0.z,q0.w, q1.x,q1.y,q1.z,q1.w,
                    q2.x,q2.y,q2.z,q2.w, q3.x,q3.y,q3.z,q3.w};
    float ms[LFD];
#pragma unroll
    for (int f = 0; f < LFD; ++f) {
      float v = a[f];
      v += __shfl_xor(v, 1); v += __shfl_xor(v, 2);   // 4-atom motif sum
      ms[f] = v;
    }
    if ((ta & 3) == 0) {                 // group leader writes (static idx only)
      float4* dst = (float4*)smfs[ta >> 2];
      dst[0] = make_float4(ms[0],  ms[1],  ms[2],  ms[3]);
      dst[1] = make_float4(ms[4],  ms[5],  ms[6],  ms[7]);
      dst[2] = make_float4(ms[8],  ms[9],  ms[10], ms[11]);
      dst[3] = make_float4(ms[12], ms[13], ms[14], ms[15]);
    }
  } else {
    // ---- wl5[f] = W_lig[f] . w5 : 8 lanes per feature, 32 ch each ----
    const int u = t - 384;               // 0..127
    const int f = u >> 3;
    const int k = u & 7;
    const float4* wlr = (const float4*)(W_lig + f * HH) + k * 8;
    const float4* w5r = (const float4*)(W_mlp + 4 * HH) + k * 8;
    float s = dot4(wlr[0], w5r[0]) + dot4(wlr[1], w5r[1])
            + dot4(wlr[2], w5r[2]) + dot4(wlr[3], w5r[3])
            + dot4(wlr[4], w5r[4]) + dot4(wlr[5], w5r[5])
            + dot4(wlr[6], w5r[6]) + dot4(wlr[7], w5r[7]);
    s += __shfl_xor(s, 1); s += __shfl_xor(s, 2); s += __shfl_xor(s, 4);
    if (k == 0) swl5[f] = s;
  }
  __syncthreads();

  // ---- combine + softmax + full stable rank, lanes 0..31 of wave 0 ----
  if (t < NMM) {
    float x = slog[t];
#pragma unroll
    for (int f = 0; f < LFD; ++f) x += smfs[t][f] * swl5[f];
    float mx = x;
    mx = fmaxf(mx, __shfl_xor(mx, 1));
    mx = fmaxf(mx, __shfl_xor(mx, 2));
    mx = fmaxf(mx, __shfl_xor(mx, 4));
    mx = fmaxf(mx, __shfl_xor(mx, 8));
    mx = fmaxf(mx, __shfl_xor(mx, 16));
    const float ex = expf(x - mx);
    float sum = ex;
    sum += __shfl_xor(sum, 1); sum += __shfl_xor(sum, 2);
    sum += __shfl_xor(sum, 4); sum += __shfl_xor(sum, 8);
    sum += __shfl_xor(sum, 16);
    const float sc = ex / sum;
    int rank = 0;
#pragma unroll
    for (int j = 0; j < NMM; ++j) {
      const float sj = __shfl(sc, j);
      rank += (sj > sc) || (sj == sc && j < t);
    }
    out[b * NMM + rank] = sc;                        // vals
    out[BB * NMM + b * NMM + rank] = (float)t;       // idx (as float)
  }
}

extern "C" void kernel_launch(void* const* d_in, const int* in_sizes, int n_in,
                              void* d_out, int out_size, void* d_ws, size_t ws_size,
                              hipStream_t stream) {
  const float* lig_feat    = (const float*)d_in[2];
  const int*   ligand_wids = (const int*)d_in[7];
  const float* W_lig       = (const float*)d_in[14];
  const float* emb_table   = (const float*)d_in[16];
  const float* W_mlp       = (const float*)d_in[18];
  float* out = (float*)d_out;

  score_kernel<<<BB, 512, 0, stream>>>(lig_feat, ligand_wids, W_lig,
                                       emb_table, W_mlp, out);
}